// Round 7
// baseline (295.012 us; speedup 1.0000x reference)
//
// R7: single cooperative kernel = zero+precompute | grid.sync | degree
// atomics | grid.sync | MFMA GEMM. Purpose: (a) remove 3 dispatch
// boundaries + memset dispatch (H1: gaps/overhead ~15-20us), (b) make our
// total cost one dispatch row so it surfaces in rocprof top-5 (H2
// diagnosis: device-atomic throughput). R6 showed privatization neutral =>
// contention is not the degree bottleneck; keep 8 copies anyway (free).
#include <hip/hip_runtime.h>
#include <hip/hip_bf16.h>
#include <hip/hip_cooperative_groups.h>

namespace cg = cooperative_groups;

#define N_NODES 100000
#define D_HID 128
#define DEG_COPIES 8
#define GRID_BLOCKS 512
#define BLOCK_THREADS 256

typedef __attribute__((ext_vector_type(8))) short bf16x8;
typedef __attribute__((ext_vector_type(4))) float f32x4;
typedef __attribute__((ext_vector_type(4))) int i32x4;

__device__ inline short f2bf(float f) {
    __hip_bfloat16 h = __float2bfloat16(f);
    return __builtin_bit_cast(short, h);
}

// ---------------------------------------------------------------------------
// Fused: phase0 zero deg + precompute WcT/bc; phase1 degree histogram;
// phase2 out[n][j] = (1+deg[n]) * (x[n,:]@Wc[:,j] + bc[j]) + b2[j] via
// mfma_f32_16x16x32_bf16 (C/D: lane holds D[row=(lane>>4)*4+reg][col=lane&15])
// ---------------------------------------------------------------------------
__global__ __launch_bounds__(BLOCK_THREADS) void gnn_fused(
    const float* __restrict__ x, const int* __restrict__ edge_dst,
    const float* __restrict__ W1, const float* __restrict__ b1,
    const float* __restrict__ W2, const float* __restrict__ b2,
    int* __restrict__ deg, unsigned short* __restrict__ WcT,
    float* __restrict__ bc, float* __restrict__ out, int E, int N)
{
    const int tid  = (int)(blockIdx.x * blockDim.x + threadIdx.x);
    const int nthr = (int)(gridDim.x * blockDim.x);

    // ---- Phase 0: zero deg copies (int4) + precompute WcT (bf16, [col][k]) ----
    {
        const i32x4 z = {0, 0, 0, 0};
        const int nquad = (DEG_COPIES * N_NODES) / 4;   // 200000
        for (int i = tid; i < nquad; i += nthr)
            ((i32x4*)deg)[i] = z;

        for (int idx = tid; idx < 64 * 64 + 64; idx += nthr) {
            if (idx < 64 * 64) {
                int i = idx >> 6;      // k of final GEMM
                int j = idx & 63;      // output col
                float s = 0.f;
                #pragma unroll 8
                for (int k = 0; k < D_HID; ++k)
                    s = fmaf(W1[i * D_HID + k], W2[k * 64 + j], s);
                WcT[j * 64 + i] = (unsigned short)f2bf(s);
            } else {
                int j = idx - 64 * 64;
                float s = 0.f;
                #pragma unroll 8
                for (int k = 0; k < D_HID; ++k)
                    s = fmaf(b1[k], W2[k * 64 + j], s);
                bc[j] = s;
            }
        }
    }
    __threadfence();
    cg::this_grid().sync();

    // ---- Phase 1: degree histogram (privatized by blockIdx&7) ----
    {
        int* mydeg = deg + (blockIdx.x & (DEG_COPIES - 1)) * N_NODES;
        const int nq = E >> 2;
        for (int i = tid; i < nq; i += nthr) {
            i32x4 v = ((const i32x4*)edge_dst)[i];
            atomicAdd(&mydeg[v.x], 1);
            atomicAdd(&mydeg[v.y], 1);
            atomicAdd(&mydeg[v.z], 1);
            atomicAdd(&mydeg[v.w], 1);
        }
        if (tid < (E & 3))   // tail (E=1M -> never taken, kept for safety)
            atomicAdd(&mydeg[edge_dst[(E & ~3) + tid]], 1);
    }
    __threadfence();
    cg::this_grid().sync();

    // ---- Phase 2: MFMA GEMM + scaled epilogue ----
    {
        const int lane = threadIdx.x & 63;
        const int wave = tid >> 6;
        const int nwaves = nthr >> 6;
        const int quad = lane >> 4;
        const int l15 = lane & 15;

        bf16x8 bfrag[4][2];
        #pragma unroll
        for (int ct = 0; ct < 4; ++ct)
            #pragma unroll
            for (int kc = 0; kc < 2; ++kc)
                bfrag[ct][kc] = *(const bf16x8*)(WcT + (16 * ct + l15) * 64 + 32 * kc + quad * 8);

        float bcv[4], b2v[4];
        #pragma unroll
        for (int ct = 0; ct < 4; ++ct) {
            bcv[ct] = bc[16 * ct + l15];
            b2v[ct] = b2[16 * ct + l15];
        }

        const int ntiles = N_NODES >> 4;   // 6250 exact
        for (int t = wave; t < ntiles; t += nwaves) {
            const int n0 = t << 4;
            const int row = n0 + l15;
            bf16x8 afrag[2];
            #pragma unroll
            for (int kc = 0; kc < 2; ++kc) {
                const float* p = x + (size_t)row * 64 + 32 * kc + quad * 8;
                f32x4 lo = *(const f32x4*)p;
                f32x4 hi = *(const f32x4*)(p + 4);
                bf16x8 a;
                #pragma unroll
                for (int j = 0; j < 4; ++j) { a[j] = f2bf(lo[j]); a[4 + j] = f2bf(hi[j]); }
                afrag[kc] = a;
            }

            f32x4 acc[4] = {{0.f,0.f,0.f,0.f},{0.f,0.f,0.f,0.f},{0.f,0.f,0.f,0.f},{0.f,0.f,0.f,0.f}};
            #pragma unroll
            for (int ct = 0; ct < 4; ++ct) {
                acc[ct] = __builtin_amdgcn_mfma_f32_16x16x32_bf16(afrag[0], bfrag[ct][0], acc[ct], 0, 0, 0);
                acc[ct] = __builtin_amdgcn_mfma_f32_16x16x32_bf16(afrag[1], bfrag[ct][1], acc[ct], 0, 0, 0);
            }

            i32x4 dsum = {0, 0, 0, 0};
            #pragma unroll
            for (int c = 0; c < DEG_COPIES; ++c)
                dsum += *(const i32x4*)(deg + (size_t)c * N_NODES + n0 + quad * 4);

            #pragma unroll
            for (int r = 0; r < 4; ++r) {
                const int rn = n0 + quad * 4 + r;
                const float s = 1.0f + (float)dsum[r];
                #pragma unroll
                for (int ct = 0; ct < 4; ++ct)
                    out[(size_t)rn * 64 + 16 * ct + l15] = fmaf(s, acc[ct][r] + bcv[ct], b2v[ct]);
            }
        }
    }
}

// ---------------------------------------------------------------------------
extern "C" void kernel_launch(void* const* d_in, const int* in_sizes, int n_in,
                              void* d_out, int out_size, void* d_ws, size_t ws_size,
                              hipStream_t stream) {
    const float* x  = (const float*)d_in[0];
    const int*   ei = (const int*)d_in[1];      // [2, E] int32
    const float* W1 = (const float*)d_in[2];
    const float* b1 = (const float*)d_in[3];
    const float* W2 = (const float*)d_in[4];
    const float* b2 = (const float*)d_in[5];
    float* out = (float*)d_out;

    int E = in_sizes[1] / 2;
    int N = N_NODES;
    const int* edge_dst = ei + E;

    // Workspace: [deg: 8*N int32][WcT: 64x64 bf16][bc: 64 f32]
    char* ws = (char*)d_ws;
    int* deg = (int*)ws;
    size_t deg_bytes = (size_t)DEG_COPIES * N * sizeof(int);
    size_t wct_off = (deg_bytes + 255) & ~(size_t)255;
    unsigned short* WcT = (unsigned short*)(ws + wct_off);
    float* bc = (float*)(ws + wct_off + 64 * 64 * sizeof(unsigned short));

    void* args[] = {
        (void*)&x, (void*)&edge_dst, (void*)&W1, (void*)&b1, (void*)&W2,
        (void*)&b2, (void*)&deg, (void*)&WcT, (void*)&bc, (void*)&out,
        (void*)&E, (void*)&N,
    };
    hipLaunchCooperativeKernel((const void*)gnn_fused, dim3(GRID_BLOCKS),
                               dim3(BLOCK_THREADS), args, 0, stream);
}

// Round 8
// 135.772 us; speedup vs baseline: 2.1728x; 2.1728x over previous
//
// R8: revert cooperative fusion (R7: two cg grid.syncs cost ~170us, kernel
// 99% stalled). Back to R6 split structure with: (1) degree+precompute merged
// into one kernel via block roles; (2) single deg copy (R4/R6: privatization
// neutral) -> memset 400KB; (3) main at 1563 blocks (~1 tile/wave), deg load
// hoisted, nontemporal out stores. Structure: memset -> histo+pre -> main.
#include <hip/hip_runtime.h>
#include <hip/hip_bf16.h>

#define N_NODES 100000
#define D_HID 128
#define DEG_BLOCKS 977            // ceil(E/4/256) for E=1e6
#define PRE_BLOCKS 17             // 4160 precompute work-items

typedef __attribute__((ext_vector_type(8))) short bf16x8;
typedef __attribute__((ext_vector_type(4))) float f32x4;
typedef __attribute__((ext_vector_type(4))) int i32x4;

__device__ inline short f2bf(float f) {
    __hip_bfloat16 h = __float2bfloat16(f);
    return __builtin_bit_cast(short, h);
}

// ---------------------------------------------------------------------------
// Kernel A: block-role split. Blocks [0, DEG_BLOCKS): degree histogram
// (int4 edge loads, device atomics into single deg copy). Blocks
// [DEG_BLOCKS, DEG_BLOCKS+PRE_BLOCKS): WcT[j][i]=bf16((W1@W2)[i][j]),
// bc = b1@W2. Independent work -> one dispatch.
// ---------------------------------------------------------------------------
__global__ __launch_bounds__(256) void histo_pre_kernel(
    const int* __restrict__ dst, int* __restrict__ deg,
    const float* __restrict__ W1, const float* __restrict__ b1,
    const float* __restrict__ W2, unsigned short* __restrict__ WcT,
    float* __restrict__ bc, int E)
{
    if (blockIdx.x < DEG_BLOCKS) {
        int i4 = (int)(blockIdx.x * blockDim.x + threadIdx.x) * 4;
        if (i4 + 3 < E) {
            i32x4 v = *(const i32x4*)(dst + i4);
            atomicAdd(&deg[v.x], 1);
            atomicAdd(&deg[v.y], 1);
            atomicAdd(&deg[v.z], 1);
            atomicAdd(&deg[v.w], 1);
        } else {
            for (int e = i4; e < E; ++e) atomicAdd(&deg[dst[e]], 1);
        }
    } else {
        int idx = (int)((blockIdx.x - DEG_BLOCKS) * blockDim.x + threadIdx.x);
        if (idx < 64 * 64) {
            int i = idx >> 6;      // k of final GEMM
            int j = idx & 63;      // output col
            float s = 0.f;
            #pragma unroll 8
            for (int k = 0; k < D_HID; ++k)
                s = fmaf(W1[i * D_HID + k], W2[k * 64 + j], s);
            WcT[j * 64 + i] = (unsigned short)f2bf(s);   // transposed [col][k]
        } else if (idx < 64 * 64 + 64) {
            int j = idx - 64 * 64;
            float s = 0.f;
            #pragma unroll 8
            for (int k = 0; k < D_HID; ++k)
                s = fmaf(b1[k], W2[k * 64 + j], s);
            bc[j] = s;
        }
    }
}

// ---------------------------------------------------------------------------
// Kernel B (MFMA): out[n][j] = (1+deg[n]) * (x[n,:]@Wc[:,j] + bc[j]) + b2[j]
// One wave per 16-node tile, mfma_f32_16x16x32_bf16.
//   C/D: lane holds D[row=(lane>>4)*4 + reg][col=lane&15]
// ---------------------------------------------------------------------------
__global__ __launch_bounds__(256) void gnn_main_mfma(
    const float* __restrict__ x, const int* __restrict__ deg,
    const unsigned short* __restrict__ WcT, const float* __restrict__ bc,
    const float* __restrict__ b2, float* __restrict__ out, int N)
{
    const int lane = threadIdx.x & 63;
    const int wave = (int)((blockIdx.x * blockDim.x + threadIdx.x) >> 6);
    const int nwaves = (int)((gridDim.x * blockDim.x) >> 6);
    const int quad = lane >> 4;
    const int l15 = lane & 15;

    // B fragments: 4 col-tiles x 2 k-chunks (16 KB total, L2-resident).
    bf16x8 bfrag[4][2];
    #pragma unroll
    for (int ct = 0; ct < 4; ++ct)
        #pragma unroll
        for (int kc = 0; kc < 2; ++kc)
            bfrag[ct][kc] = *(const bf16x8*)(WcT + (16 * ct + l15) * 64 + 32 * kc + quad * 8);

    float bcv[4], b2v[4];
    #pragma unroll
    for (int ct = 0; ct < 4; ++ct) {
        bcv[ct] = bc[16 * ct + l15];
        b2v[ct] = b2[16 * ct + l15];
    }

    const int ntiles = N >> 4;      // 100000/16 = 6250 exact
    for (int t = wave; t < ntiles; t += nwaves) {
        const int n0 = t << 4;
        const int row = n0 + l15;

        // Hoist deg load: independent of MFMA chain, overlaps its latency.
        i32x4 dsum = *(const i32x4*)(deg + n0 + quad * 4);

        bf16x8 afrag[2];
        #pragma unroll
        for (int kc = 0; kc < 2; ++kc) {
            const float* p = x + (size_t)row * 64 + 32 * kc + quad * 8;
            f32x4 lo = *(const f32x4*)p;
            f32x4 hi = *(const f32x4*)(p + 4);
            bf16x8 a;
            #pragma unroll
            for (int j = 0; j < 4; ++j) { a[j] = f2bf(lo[j]); a[4 + j] = f2bf(hi[j]); }
            afrag[kc] = a;
        }

        f32x4 acc[4] = {{0.f,0.f,0.f,0.f},{0.f,0.f,0.f,0.f},{0.f,0.f,0.f,0.f},{0.f,0.f,0.f,0.f}};
        #pragma unroll
        for (int ct = 0; ct < 4; ++ct) {
            acc[ct] = __builtin_amdgcn_mfma_f32_16x16x32_bf16(afrag[0], bfrag[ct][0], acc[ct], 0, 0, 0);
            acc[ct] = __builtin_amdgcn_mfma_f32_16x16x32_bf16(afrag[1], bfrag[ct][1], acc[ct], 0, 0, 0);
        }

        // Epilogue: row rn = n0 + quad*4 + r, col = 16*ct + l15.
        // out has zero reuse -> nontemporal stores keep L2 for x/WcT.
        #pragma unroll
        for (int r = 0; r < 4; ++r) {
            const int rn = n0 + quad * 4 + r;
            const float s = 1.0f + (float)dsum[r];
            #pragma unroll
            for (int ct = 0; ct < 4; ++ct)
                __builtin_nontemporal_store(fmaf(s, acc[ct][r] + bcv[ct], b2v[ct]),
                                            out + (size_t)rn * 64 + 16 * ct + l15);
        }
    }
}

// ---------------------------------------------------------------------------
extern "C" void kernel_launch(void* const* d_in, const int* in_sizes, int n_in,
                              void* d_out, int out_size, void* d_ws, size_t ws_size,
                              hipStream_t stream) {
    const float* x  = (const float*)d_in[0];
    const int*   ei = (const int*)d_in[1];      // [2, E] int32
    const float* W1 = (const float*)d_in[2];
    const float* b1 = (const float*)d_in[3];
    const float* W2 = (const float*)d_in[4];
    const float* b2 = (const float*)d_in[5];
    float* out = (float*)d_out;

    const int E = in_sizes[1] / 2;
    const int N = N_NODES;
    const int* edge_dst = ei + E;

    // Workspace: [deg: N int32][WcT: 64x64 bf16][bc: 64 f32]
    char* ws = (char*)d_ws;
    int* deg = (int*)ws;
    size_t deg_bytes = (size_t)N * sizeof(int);
    size_t wct_off = (deg_bytes + 255) & ~(size_t)255;
    unsigned short* WcT = (unsigned short*)(ws + wct_off);
    float* bc = (float*)(ws + wct_off + 64 * 64 * sizeof(unsigned short));

    hipMemsetAsync(deg, 0, deg_bytes, stream);

    histo_pre_kernel<<<DEG_BLOCKS + PRE_BLOCKS, 256, 0, stream>>>(
        edge_dst, deg, W1, b1, W2, WcT, bc, E);
    gnn_main_mfma<<<1563, 256, 0, stream>>>(x, deg, WcT, bc, b2, out, N);
}